// Round 13
// baseline (2608.699 us; speedup 1.0000x reference)
//
#include <hip/hip_runtime.h>

// GRU decoder, B=256, H=512, T=512. 16 groups x 16 members = 256 WGs (1/CU).
// Round-13: SELF-VALIDATING exchange. Each exported u64 = {2 bf16-hi | tag}.
// No flag, no drain, no csum (r12 failed: flag raced ahead of data ->
// retry storm). Consumers sweep peers' u64s until all 16 tags == t+1; the
// detecting sweep already holds the data -> flag-detect + reload collapse
// into ONE coherence-point trip. Parity double-buffer as r4-r8. Waves 0-3:
// capture 4 peers each (16 u64/lane) -> swizzled LDS. Waves 4-5: gates,
// export, out-store (drained at final barrier, overlapped with sweeps).

typedef __attribute__((ext_vector_type(8))) short short8;
typedef __attribute__((ext_vector_type(4))) float f32x4;
typedef __attribute__((ext_vector_type(4))) unsigned int u32x4;
typedef unsigned short ushort_t;
typedef unsigned int uint_t;
typedef unsigned long long u64_t;

#define NG 16
#define NM 16
#define NB 16
#define NJ 32
#define TPB 384
#define SWEEP_MAX 8192u
#define ABORT_IDX 8192  // u32 idx (byte 32768) in control region
#define GBUF_BASE 16384 // u32 idx of data region (byte 65536)
#define PAR_U64 65536   // u64 per parity: 16 groups * 16 members * 256
#define GRP_U64 4096    // u64 per group

#define ALD(P) __hip_atomic_load((P), __ATOMIC_RELAXED, __HIP_MEMORY_SCOPE_AGENT)
#define AST(P, V) __hip_atomic_store((P), (V), __ATOMIC_RELAXED, __HIP_MEMORY_SCOPE_AGENT)

__device__ __forceinline__ ushort_t bf16_rne(float f) {
  uint_t u = __float_as_uint(f);
  return (ushort_t)((u + 0x7fffu + ((u >> 16) & 1u)) >> 16);
}
__device__ __forceinline__ float bf16f(ushort_t h) {
  return __uint_as_float(((uint_t)h) << 16);
}
__device__ __forceinline__ int gRow(int rs, int m) {
  int base = m * NJ;
  if (rs < 32) return base + rs;
  if (rs < 64) return 512 + base + (rs - 32);
  return 1024 + base + (rs - 64);
}

template <bool LO>
__device__ __forceinline__ void loadW(short8* dst, const float* __restrict__ W,
                                      int tile, int m, int lane) {
  int rs = tile * 16 + (lane & 15);
  const float* p = W + (size_t)gRow(rs, m) * 512 + ((lane >> 4) << 3);
#pragma unroll
  for (int c = 0; c < 16; ++c) {
    const float* pc = p + c * 32;
    short8 o;
#pragma unroll
    for (int i = 0; i < 8; ++i) {
      float v = pc[i];
      ushort_t hi = bf16_rne(v);
      o[i] = LO ? (short)bf16_rne(v - bf16f(hi)) : (short)hi;
    }
    dst[c] = o;
  }
}

__global__ __launch_bounds__(TPB, 1) void gru_kernel(
    const float* __restrict__ x, const float* __restrict__ Wih,
    const float* __restrict__ Whh, const float* __restrict__ bih,
    const float* __restrict__ bhh, float* __restrict__ out,
    uint_t* __restrict__ wsp, int NT) {
  __shared__ __align__(16) uint_t s_pb[4096];  // 16KB: 16 chunks x 1KB (hi)
  __shared__ __align__(16) uint_t s_xlo[4096]; // x lo-planes (gi phase only)
  __shared__ float s_gi[96 * 17];
  __shared__ float s_gh[96 * 17];
  __shared__ float s_hloc[NB * NJ]; // own h slice, f32 across steps
  __shared__ float s_bhh[NJ];
  __shared__ int s_stop;

  const int tid = threadIdx.x;
  const int lane = tid & 63;
  const int w = tid >> 6;
  const int bid = blockIdx.x;
  const int g = bid & 15;
  const int m = bid >> 4;
  if (NT <= 0) return;

  uint_t* flagsu = wsp;
  u64_t* gq = (u64_t*)(wsp + GBUF_BASE);

  // ---- stage relu(x) as hi plane (s_pb) + lo plane (s_xlo) ----
  for (int i = tid; i < 1024; i += TPB) {
    int b = i >> 6, k0 = (i & 63) << 3;
    const float* px = x + (size_t)(g * NB + b) * 512 + k0;
    u32x4 vh, vl;
#pragma unroll
    for (int jj = 0; jj < 4; ++jj) {
      float f0 = px[2 * jj], f1 = px[2 * jj + 1];
      f0 = f0 > 0.f ? f0 : 0.f;
      f1 = f1 > 0.f ? f1 : 0.f;
      ushort_t h0 = bf16_rne(f0), h1 = bf16_rne(f1);
      vh[jj] = (uint_t)h0 | ((uint_t)h1 << 16);
      vl[jj] = (uint_t)bf16_rne(f0 - bf16f(h0)) |
               ((uint_t)bf16_rne(f1 - bf16f(h1)) << 16);
    }
    int c = k0 >> 5, kk = k0 & 31;
    int base = c * 1024 + ((((b << 6) + (kk << 1))) ^ ((b & 7) << 4));
    *(u32x4*)((char*)s_pb + base) = vh;
    *(u32x4*)((char*)s_xlo + base) = vl;
  }
  if (tid < NJ) s_bhh[tid] = bhh[1024 + m * NJ + tid];
  if (tid == 0) s_stop = 0;
  __syncthreads();

  short8 wA[16], wB[16];
  const f32x4 vzero = {0.f, 0.f, 0.f, 0.f};
  const int bcol = lane & 15;
  const int roff = ((bcol << 6) + ((lane >> 4) << 4)) ^ ((bcol & 7) << 4);
  const char* pb = (const char*)s_pb;
  const char* pxl = (const char*)s_xlo;

  // ---- gi = relu(x) @ W_ih^T (3-term hi/lo split) ----
  f32x4 acc0 = vzero, acc1 = vzero;
  if (w < 3) {
    loadW<false>(wA, Wih, 2 * w, m, lane);
    loadW<false>(wB, Wih, 2 * w + 1, m, lane);
    {
      f32x4 a0h = vzero, a0l = vzero, a1h = vzero, a1l = vzero;
#pragma unroll
      for (int c = 0; c < 16; ++c) {
        short8 bh = *(const short8*)(pb + c * 1024 + roff);
        short8 bl = *(const short8*)(pxl + c * 1024 + roff);
        a0h = __builtin_amdgcn_mfma_f32_16x16x32_bf16(wA[c], bh, a0h, 0, 0, 0);
        a1h = __builtin_amdgcn_mfma_f32_16x16x32_bf16(wB[c], bh, a1h, 0, 0, 0);
        a0l = __builtin_amdgcn_mfma_f32_16x16x32_bf16(wA[c], bl, a0l, 0, 0, 0);
        a1l = __builtin_amdgcn_mfma_f32_16x16x32_bf16(wB[c], bl, a1l, 0, 0, 0);
      }
      acc0 = a0h + a0l;
      acc1 = a1h + a1l;
    }
    loadW<true>(wA, Wih, 2 * w, m, lane);
    loadW<true>(wB, Wih, 2 * w + 1, m, lane);
#pragma unroll
    for (int c = 0; c < 16; ++c) {
      short8 bh = *(const short8*)(pb + c * 1024 + roff);
      acc0 = __builtin_amdgcn_mfma_f32_16x16x32_bf16(wA[c], bh, acc0, 0, 0, 0);
      acc1 = __builtin_amdgcn_mfma_f32_16x16x32_bf16(wB[c], bh, acc1, 0, 0, 0);
    }
  }
  __syncthreads();
  if (w < 3) {
    int drow = (lane >> 4) << 2;
#pragma unroll
    for (int q = 0; q < 4; ++q) {
      int rs0 = 2 * w * 16 + drow + q, rs1 = rs0 + 16;
      int g0 = gRow(rs0, m), g1 = gRow(rs1, m);
      s_gi[rs0 * 17 + bcol] = acc0[q] + bih[g0] + (rs0 < 64 ? bhh[g0] : 0.f);
      s_gi[rs1 * 17 + bcol] = acc1[q] + bih[g1] + (rs1 < 64 ? bhh[g1] : 0.f);
    }
    loadW<false>(wA, Whh, 2 * w, m, lane); // W_hh resident from here
    loadW<false>(wB, Whh, 2 * w + 1, m, lane);
  }
  for (int i = tid; i < 4096; i += TPB) s_pb[i] = 0u; // h0 = 0
  for (int i = tid; i < NB * NJ; i += TPB) s_hloc[i] = 0.f;
  __syncthreads();

  const size_t outRow = (size_t)NT * 512;
  float* outBase = out + (size_t)(g * NB) * outRow + m * NJ;

  for (int t = 0; t < NT; ++t) {
    const int par = (t + 1) & 1;
    // ---- phase 1: gh = W_hh @ h_hi from LDS chunks (waves 0-2) ----
    if (w < 3) {
      f32x4 aE0 = vzero, aO0 = vzero, aE1 = vzero, aO1 = vzero;
#pragma unroll
      for (int p = 0; p < 16; p += 2) {
        short8 b0 = *(const short8*)(pb + p * 1024 + roff);
        short8 b1 = *(const short8*)(pb + (p + 1) * 1024 + roff);
        aE0 = __builtin_amdgcn_mfma_f32_16x16x32_bf16(wA[p], b0, aE0, 0, 0, 0);
        aE1 = __builtin_amdgcn_mfma_f32_16x16x32_bf16(wB[p], b0, aE1, 0, 0, 0);
        aO0 = __builtin_amdgcn_mfma_f32_16x16x32_bf16(wA[p + 1], b1, aO0, 0, 0, 0);
        aO1 = __builtin_amdgcn_mfma_f32_16x16x32_bf16(wB[p + 1], b1, aO1, 0, 0, 0);
      }
      f32x4 r0 = aE0 + aO0, r1 = aE1 + aO1;
      int drow = (lane >> 4) << 2;
#pragma unroll
      for (int q = 0; q < 4; ++q) {
        s_gh[(2 * w * 16 + drow + q) * 17 + bcol] = r0[q];
        s_gh[((2 * w + 1) * 16 + drow + q) * 17 + bcol] = r1[q];
      }
    }
    __syncthreads();

    // ---- waves 4-5: gates -> tagged-u64 export -> out store ----
    const int et = tid - 256;
    if (et >= 0) {
      int b = et >> 3, j0 = (et & 7) << 2;
      float hn[4];
#pragma unroll
      for (int e = 0; e < 4; ++e) {
        int j = j0 + e;
        float pr = s_gi[j * 17 + b] + s_gh[j * 17 + b];
        float pz = s_gi[(32 + j) * 17 + b] + s_gh[(32 + j) * 17 + b];
        float r = 1.f / (1.f + __expf(-pr));
        float z = 1.f / (1.f + __expf(-pz));
        float pn =
            s_gi[(64 + j) * 17 + b] + r * (s_gh[(64 + j) * 17 + b] + s_bhh[j]);
        float n = 1.f - 2.f / (1.f + __expf(2.f * pn));
        hn[e] = n + z * (s_hloc[b * 32 + j] - n);
        s_hloc[b * 32 + j] = hn[e];
      }
      const u64_t tag = (u64_t)(uint_t)(t + 1) << 32;
      uint_t d0 = (uint_t)bf16_rne(hn[0]) | ((uint_t)bf16_rne(hn[1]) << 16);
      uint_t d1 = (uint_t)bf16_rne(hn[2]) | ((uint_t)bf16_rne(hn[3]) << 16);
      u64_t* dst = gq + (size_t)par * PAR_U64 + g * GRP_U64 + m * 256 +
                   b * 16 + ((et & 7) << 1);
      AST(dst, (u64_t)d0 | tag);
      AST(dst + 1, (u64_t)d1 | tag);
      f32x4 ov = {hn[0], hn[1], hn[2], hn[3]};
      __builtin_nontemporal_store(
          ov, (f32x4*)(outBase + (size_t)b * outRow + (size_t)t * 512 + j0));
    }

    // ---- waves 0-3: sweep-capture 4 peers each (16 tagged u64/lane) ----
    if (w < 4 && t + 1 < NT) {
      const uint_t tgt = (uint_t)(t + 1);
      const int p = (w << 2) + (lane >> 4); // global peer/chunk index
      const int kp = lane & 15;
      const u64_t* src =
          gq + (size_t)par * PAR_U64 + g * GRP_U64 + p * 256 + kp;
      u64_t q0, q1, q2, q3, q4, q5, q6, q7, q8, q9, qA, qB, qC, qD, qE, qF;
      int good = 0;
      uint_t sweeps = 0;
      __builtin_amdgcn_s_sleep(6); // data can't land before gates+flight
      for (;;) {
        q0 = ALD(src + 0 * 16);  q1 = ALD(src + 1 * 16);
        q2 = ALD(src + 2 * 16);  q3 = ALD(src + 3 * 16);
        q4 = ALD(src + 4 * 16);  q5 = ALD(src + 5 * 16);
        q6 = ALD(src + 6 * 16);  q7 = ALD(src + 7 * 16);
        q8 = ALD(src + 8 * 16);  q9 = ALD(src + 9 * 16);
        qA = ALD(src + 10 * 16); qB = ALD(src + 11 * 16);
        qC = ALD(src + 12 * 16); qD = ALD(src + 13 * 16);
        qE = ALD(src + 14 * 16); qF = ALD(src + 15 * 16);
        uint_t ok =
            ((uint_t)(q0 >> 32) == tgt) & ((uint_t)(q1 >> 32) == tgt) &
            ((uint_t)(q2 >> 32) == tgt) & ((uint_t)(q3 >> 32) == tgt) &
            ((uint_t)(q4 >> 32) == tgt) & ((uint_t)(q5 >> 32) == tgt) &
            ((uint_t)(q6 >> 32) == tgt) & ((uint_t)(q7 >> 32) == tgt) &
            ((uint_t)(q8 >> 32) == tgt) & ((uint_t)(q9 >> 32) == tgt) &
            ((uint_t)(qA >> 32) == tgt) & ((uint_t)(qB >> 32) == tgt) &
            ((uint_t)(qC >> 32) == tgt) & ((uint_t)(qD >> 32) == tgt) &
            ((uint_t)(qE >> 32) == tgt) & ((uint_t)(qF >> 32) == tgt);
        if (__all((int)ok)) {
          good = 1;
          break;
        }
        ++sweeps;
        uint_t ab = 0;
        if ((sweeps & 7u) == 0u) {
          ab = ALD(&flagsu[ABORT_IDX]);
          if (sweeps > SWEEP_MAX) {
            AST(&flagsu[ABORT_IDX], 1u);
            ab = 1;
          }
        }
        if (__any((int)(ab != 0))) {
          if (lane == 0) s_stop = 1;
          break;
        }
        __builtin_amdgcn_s_sleep(2);
      }
      if (good) { // write captured data to swizzled LDS chunk p
#define STW(b, qq)                                                             \
  *(uint_t*)((char*)s_pb + p * 1024 +                                          \
             ((((b) << 6) + (kp << 2)) ^ (((b)&7) << 4))) = (uint_t)(qq);
        STW(0, q0)  STW(1, q1)  STW(2, q2)  STW(3, q3)
        STW(4, q4)  STW(5, q5)  STW(6, q6)  STW(7, q7)
        STW(8, q8)  STW(9, q9)  STW(10, qA) STW(11, qB)
        STW(12, qC) STW(13, qD) STW(14, qE) STW(15, qF)
#undef STW
      }
    }
    __syncthreads();
    if (s_stop) break;
  }
}

extern "C" void kernel_launch(void* const* d_in, const int* in_sizes, int n_in,
                              void* d_out, int out_size, void* d_ws,
                              size_t ws_size, hipStream_t stream) {
  const float* x = (const float*)d_in[0];
  const float* Wih = (const float*)d_in[1];
  const float* Whh = (const float*)d_in[2];
  const float* bih = (const float*)d_in[3];
  const float* bhh = (const float*)d_in[4];
  float* out = (float*)d_out;
  int NT = out_size / (256 * 512);
  // ws: [0,64KB) control (abort @32KB; tags self-validate, poison is fine);
  // data @64KB: 2 parities x 512KB tagged-u64 exchange.
  uint_t* wsp = (uint_t*)d_ws;
  (void)hipMemsetAsync(d_ws, 0, 65536, stream);
  hipLaunchKernelGGL(gru_kernel, dim3(NG * NM), dim3(TPB), 0, stream, x, Wih,
                     Whh, bih, bhh, out, wsp, NT);
}

// Round 17
// 2022.287 us; speedup vs baseline: 1.2900x; 1.2900x over previous
//
#include <hip/hip_runtime.h>

// GRU decoder, B=256, H=512, T=512. 16 groups x 16 members = 256 WGs (1/CU).
// Round-14 design (4th submission: r14-r16 all died on a dead container
// before source transmission). ONE barrier/step, TWO coherence trips.
//  - gates waves (4-5): gates -> export (relaxed sc1, r11 layout) ->
//    per-wave vmcnt(0) drain -> own flag (2/member) -> out store.
//  - MFMA waves (0-2): poll 32 flags (overlapped with local gates), then
//    batch-load 32 u64 B-frag words DIRECT to registers (r6's verified
//    layout, batched = one latency exposure) -> MFMA -> s_gh[parity].
//  - s_gh double-buffered by parity; flag check uses >= (peers run ahead);
//    2-parity exchange buffer; bounded spin + abort cascade.
// r12/r13 lesson encoded: never signal readiness before data is drained.

typedef __attribute__((ext_vector_type(8))) short short8;
typedef __attribute__((ext_vector_type(4))) float f32x4;
typedef __attribute__((ext_vector_type(4))) unsigned int u32x4;
typedef unsigned short ushort_t;
typedef unsigned int uint_t;
typedef unsigned long long u64_t;

#define NG 16
#define NM 16
#define NB 16
#define NJ 32
#define TPB 384
#define SPIN_MAX (1u << 15)
#define ABORT_IDX 8192  // u32 idx (byte 32768) in control region
#define GBUF_BASE 16384 // u32 idx of data region (byte 65536)
#define PAR_U64 32768   // u64 per parity: 16 groups * 16 members * 128
#define GRP_U64 2048    // u64 per group

#define ALD(P) __hip_atomic_load((P), __ATOMIC_RELAXED, __HIP_MEMORY_SCOPE_AGENT)
#define AST(P, V) __hip_atomic_store((P), (V), __ATOMIC_RELAXED, __HIP_MEMORY_SCOPE_AGENT)
#define VMWAIT()                                                               \
  do {                                                                         \
    asm volatile("s_waitcnt vmcnt(0)" ::: "memory");                           \
    __builtin_amdgcn_sched_barrier(0);                                         \
  } while (0)

__device__ __forceinline__ ushort_t bf16_rne(float f) {
  uint_t u = __float_as_uint(f);
  return (ushort_t)((u + 0x7fffu + ((u >> 16) & 1u)) >> 16);
}
__device__ __forceinline__ float bf16f(ushort_t h) {
  return __uint_as_float(((uint_t)h) << 16);
}
__device__ __forceinline__ short8 mk8(u64_t a, u64_t b) {
  union {
    u64_t q[2];
    short8 s;
  } u;
  u.q[0] = a;
  u.q[1] = b;
  return u.s;
}
__device__ __forceinline__ int gRow(int rs, int m) {
  int base = m * NJ;
  if (rs < 32) return base + rs;
  if (rs < 64) return 512 + base + (rs - 32);
  return 1024 + base + (rs - 64);
}

template <bool LO>
__device__ __forceinline__ void loadW(short8* dst, const float* __restrict__ W,
                                      int tile, int m, int lane) {
  int rs = tile * 16 + (lane & 15);
  const float* p = W + (size_t)gRow(rs, m) * 512 + ((lane >> 4) << 3);
#pragma unroll
  for (int c = 0; c < 16; ++c) {
    const float* pc = p + c * 32;
    short8 o;
#pragma unroll
    for (int i = 0; i < 8; ++i) {
      float v = pc[i];
      ushort_t hi = bf16_rne(v);
      o[i] = LO ? (short)bf16_rne(v - bf16f(hi)) : (short)hi;
    }
    dst[c] = o;
  }
}

__global__ __launch_bounds__(TPB, 1) void gru_kernel(
    const float* __restrict__ x, const float* __restrict__ Wih,
    const float* __restrict__ Whh, const float* __restrict__ bih,
    const float* __restrict__ bhh, float* __restrict__ out,
    uint_t* __restrict__ wsp, int NT) {
  __shared__ __align__(16) uint_t s_pb[4096];  // x hi staging (gi phase only)
  __shared__ __align__(16) uint_t s_xlo[4096]; // x lo staging (gi phase only)
  __shared__ float s_gi[96 * 17];
  __shared__ float s_gh[2][96 * 17]; // parity double-buffered gh
  __shared__ float s_hloc[NB * NJ];  // own h slice, f32 across steps
  __shared__ float s_bhh[NJ];
  __shared__ int s_stop;

  const int tid = threadIdx.x;
  const int lane = tid & 63;
  const int w = tid >> 6;
  const int bid = blockIdx.x;
  const int g = bid & 15;
  const int m = bid >> 4;
  const int me = (g << 4) + m;
  if (NT <= 0) return;

  uint_t* flagsu = wsp;
  u64_t* gq = (u64_t*)(wsp + GBUF_BASE);

  // ---- stage relu(x) as hi/lo planes ----
  for (int i = tid; i < 1024; i += TPB) {
    int b = i >> 6, k0 = (i & 63) << 3;
    const float* px = x + (size_t)(g * NB + b) * 512 + k0;
    u32x4 vh, vl;
#pragma unroll
    for (int jj = 0; jj < 4; ++jj) {
      float f0 = px[2 * jj], f1 = px[2 * jj + 1];
      f0 = f0 > 0.f ? f0 : 0.f;
      f1 = f1 > 0.f ? f1 : 0.f;
      ushort_t h0 = bf16_rne(f0), h1 = bf16_rne(f1);
      vh[jj] = (uint_t)h0 | ((uint_t)h1 << 16);
      vl[jj] = (uint_t)bf16_rne(f0 - bf16f(h0)) |
               ((uint_t)bf16_rne(f1 - bf16f(h1)) << 16);
    }
    int c = k0 >> 5, kk = k0 & 31;
    int base = c * 1024 + ((((b << 6) + (kk << 1))) ^ ((b & 7) << 4));
    *(u32x4*)((char*)s_pb + base) = vh;
    *(u32x4*)((char*)s_xlo + base) = vl;
  }
  if (tid < NJ) s_bhh[tid] = bhh[1024 + m * NJ + tid];
  if (tid == 0) s_stop = 0;
  __syncthreads();

  short8 wA[16], wB[16];
  const f32x4 vzero = {0.f, 0.f, 0.f, 0.f};
  const int bcol = lane & 15;
  const int roff = ((bcol << 6) + ((lane >> 4) << 4)) ^ ((bcol & 7) << 4);
  const char* pb = (const char*)s_pb;
  const char* pxl = (const char*)s_xlo;

  // ---- gi = relu(x) @ W_ih^T (3-term hi/lo split) ----
  f32x4 acc0 = vzero, acc1 = vzero;
  if (w < 3) {
    loadW<false>(wA, Wih, 2 * w, m, lane);
    loadW<false>(wB, Wih, 2 * w + 1, m, lane);
    {
      f32x4 a0h = vzero, a0l = vzero, a1h = vzero, a1l = vzero;
#pragma unroll
      for (int c = 0; c < 16; ++c) {
        short8 bh = *(const short8*)(pb + c * 1024 + roff);
        short8 bl = *(const short8*)(pxl + c * 1024 + roff);
        a0h = __builtin_amdgcn_mfma_f32_16x16x32_bf16(wA[c], bh, a0h, 0, 0, 0);
        a1h = __builtin_amdgcn_mfma_f32_16x16x32_bf16(wB[c], bh, a1h, 0, 0, 0);
        a0l = __builtin_amdgcn_mfma_f32_16x16x32_bf16(wA[c], bl, a0l, 0, 0, 0);
        a1l = __builtin_amdgcn_mfma_f32_16x16x32_bf16(wB[c], bl, a1l, 0, 0, 0);
      }
      acc0 = a0h + a0l;
      acc1 = a1h + a1l;
    }
    loadW<true>(wA, Wih, 2 * w, m, lane);
    loadW<true>(wB, Wih, 2 * w + 1, m, lane);
#pragma unroll
    for (int c = 0; c < 16; ++c) {
      short8 bh = *(const short8*)(pb + c * 1024 + roff);
      acc0 = __builtin_amdgcn_mfma_f32_16x16x32_bf16(wA[c], bh, acc0, 0, 0, 0);
      acc1 = __builtin_amdgcn_mfma_f32_16x16x32_bf16(wB[c], bh, acc1, 0, 0, 0);
    }
  }
  __syncthreads();
  if (w < 3) {
    int drow = (lane >> 4) << 2;
#pragma unroll
    for (int q = 0; q < 4; ++q) {
      int rs0 = 2 * w * 16 + drow + q, rs1 = rs0 + 16;
      int g0 = gRow(rs0, m), g1 = gRow(rs1, m);
      s_gi[rs0 * 17 + bcol] = acc0[q] + bih[g0] + (rs0 < 64 ? bhh[g0] : 0.f);
      s_gi[rs1 * 17 + bcol] = acc1[q] + bih[g1] + (rs1 < 64 ? bhh[g1] : 0.f);
    }
    loadW<false>(wA, Whh, 2 * w, m, lane); // W_hh resident from here
    loadW<false>(wB, Whh, 2 * w + 1, m, lane);
  }
  for (int i = tid; i < 96 * 17; i += TPB) s_gh[0][i] = 0.f; // gh(h0)=0
  for (int i = tid; i < NB * NJ; i += TPB) s_hloc[i] = 0.f;
  __syncthreads();

  const size_t outRow = (size_t)NT * 512;
  float* outBase = out + (size_t)(g * NB) * outRow + m * NJ;
  const int lofs = ((lane & 15) << 3) + ((lane >> 4) << 1); // u64 B-frag offs

  for (int t = 0; t < NT; ++t) {
    const int xpar = (t + 1) & 1;
    // ---- gates (waves 4-5): h(t+1); export+drain+flag; out ----
    const int et = tid - 256;
    if (et >= 0) {
      const float* ghp = s_gh[t & 1];
      int b = et >> 3, j0 = (et & 7) << 2;
      float hn[4];
#pragma unroll
      for (int e = 0; e < 4; ++e) {
        int j = j0 + e;
        float pr = s_gi[j * 17 + b] + ghp[j * 17 + b];
        float pz = s_gi[(32 + j) * 17 + b] + ghp[(32 + j) * 17 + b];
        float r = 1.f / (1.f + __expf(-pr));
        float z = 1.f / (1.f + __expf(-pz));
        float pn =
            s_gi[(64 + j) * 17 + b] + r * (ghp[(64 + j) * 17 + b] + s_bhh[j]);
        float n = 1.f - 2.f / (1.f + __expf(2.f * pn));
        hn[e] = n + z * (s_hloc[b * 32 + j] - n);
        s_hloc[b * 32 + j] = hn[e];
      }
      if (t + 1 < NT) {
        uint_t d0 = (uint_t)bf16_rne(hn[0]) | ((uint_t)bf16_rne(hn[1]) << 16);
        uint_t d1 = (uint_t)bf16_rne(hn[2]) | ((uint_t)bf16_rne(hn[3]) << 16);
        u64_t pq = (u64_t)d0 | ((u64_t)d1 << 32);
        u64_t* dst = gq + (size_t)xpar * PAR_U64 + g * GRP_U64 + (m << 7) +
                     (b << 3) + (et & 7);
        AST(dst, pq);
        VMWAIT(); // own exports acked at coherence point
        if (lane == 0)
          AST(&flagsu[(me << 5) + ((w - 4) << 3)], (uint_t)(t + 1));
      }
      f32x4 ov = {hn[0], hn[1], hn[2], hn[3]};
      __builtin_nontemporal_store(
          ov, (f32x4*)(outBase + (size_t)b * outRow + (size_t)t * 512 + j0));
    }

    // ---- MFMA waves (0-2): poll flags, batch-load B-frags, gh(t+1) ----
    if (w < 3 && t + 1 < NT) {
      const uint_t tgt = (uint_t)(t + 1);
      int aborted = 0;
      {
        uint_t sp = 0;
        uint_t* fp =
            flagsu + ((((g << 4) + (lane >> 1)) << 5) + ((lane & 1) << 3));
        for (;;) {
          uint_t v = tgt;
          if (lane < 32) v = ALD(fp);
          if (__all((int)(v >= tgt))) break;
          ++sp;
          uint_t ab = 0;
          if ((sp & 15u) == 0u) {
            ab = ALD(&flagsu[ABORT_IDX]);
            if (sp > SPIN_MAX) {
              AST(&flagsu[ABORT_IDX], 1u);
              ab = 1;
            }
          }
          if (__any((int)(ab != 0))) {
            if (lane == 0) s_stop = 1;
            aborted = 1;
            break;
          }
          __builtin_amdgcn_s_sleep(1);
        }
      }
      if (!aborted) {
        const u64_t* src =
            gq + (size_t)xpar * PAR_U64 + g * GRP_U64 + lofs;
        u64_t qv[32];
#pragma unroll
        for (int p = 0; p < 16; ++p) { // all 32 loads in flight together
          qv[2 * p] = ALD(src + (p << 7));
          qv[2 * p + 1] = ALD(src + (p << 7) + 1);
        }
        f32x4 aE0 = vzero, aO0 = vzero, aE1 = vzero, aO1 = vzero;
#pragma unroll
        for (int p = 0; p < 16; p += 2) {
          short8 b0 = mk8(qv[2 * p], qv[2 * p + 1]);
          short8 b1 = mk8(qv[2 * p + 2], qv[2 * p + 3]);
          aE0 = __builtin_amdgcn_mfma_f32_16x16x32_bf16(wA[p], b0, aE0, 0, 0, 0);
          aE1 = __builtin_amdgcn_mfma_f32_16x16x32_bf16(wB[p], b0, aE1, 0, 0, 0);
          aO0 = __builtin_amdgcn_mfma_f32_16x16x32_bf16(wA[p + 1], b1, aO0, 0, 0, 0);
          aO1 = __builtin_amdgcn_mfma_f32_16x16x32_bf16(wB[p + 1], b1, aO1, 0, 0, 0);
        }
        f32x4 r0 = aE0 + aO0, r1 = aE1 + aO1;
        float* ghn = s_gh[xpar];
        int drow = (lane >> 4) << 2;
#pragma unroll
        for (int q = 0; q < 4; ++q) {
          ghn[(2 * w * 16 + drow + q) * 17 + bcol] = r0[q];
          ghn[((2 * w + 1) * 16 + drow + q) * 17 + bcol] = r1[q];
        }
      }
    }
    __syncthreads();
    if (s_stop) break;
  }
}

extern "C" void kernel_launch(void* const* d_in, const int* in_sizes, int n_in,
                              void* d_out, int out_size, void* d_ws,
                              size_t ws_size, hipStream_t stream) {
  const float* x = (const float*)d_in[0];
  const float* Wih = (const float*)d_in[1];
  const float* Whh = (const float*)d_in[2];
  const float* bih = (const float*)d_in[3];
  const float* bhh = (const float*)d_in[4];
  float* out = (float*)d_out;
  int NT = out_size / (256 * 512);
  // ws: [0,64KB) flags (2/member, 128B line) + abort @32KB;
  // data @64KB: 2 parities x 256KB (hi-plane h exchange).
  uint_t* wsp = (uint_t*)d_ws;
  (void)hipMemsetAsync(d_ws, 0, 65536, stream);
  hipLaunchKernelGGL(gru_kernel, dim3(NG * NM), dim3(TPB), 0, stream, x, Wih,
                     Whh, bih, bhh, out, wsp, NT);
}

// Round 18
// 1391.422 us; speedup vs baseline: 1.8748x; 1.4534x over previous
//
#include <hip/hip_runtime.h>

// GRU decoder, B=256, H=512, T=512. 16 groups x 16 members = 256 WGs (1/CU).
// Round-18 = r11 skeleton (proven best, 1161us) + r17's PROVEN per-wave
// drain+flag, minus r11's block-wide drain barrier:
//  phase1 (waves 0-2): MFMA from s_pb LDS -> s_gh.  barrier#1.
//  gates (waves 4-5): gates -> export 1 u64/thr (sc1) -> vmcnt(0) drain ->
//    own flag (2/member) -> out store (drains at barrier#2).
//  pollers (waves 0-3, concurrent): poll 4 peers x 2 flags, then r11's
//    batched reload (8 u64/lane, low reg pressure) -> swizzled LDS.
//  barrier#2. 2 barriers/step; producer drain overlapped with polling.
// r17 lesson: direct-to-reg B-frag batch (32 u64) spills against resident
// weights -> keep the LDS staging path (8 u64/lane max in flight).

typedef __attribute__((ext_vector_type(8))) short short8;
typedef __attribute__((ext_vector_type(4))) float f32x4;
typedef __attribute__((ext_vector_type(4))) unsigned int u32x4;
typedef unsigned short ushort_t;
typedef unsigned int uint_t;
typedef unsigned long long u64_t;

#define NG 16
#define NM 16
#define NB 16
#define NJ 32
#define TPB 384
#define SPIN_MAX (1u << 16)
#define ABORT_IDX 8192  // u32 idx (byte 32768) in control region
#define GBUF_BASE 16384 // u32 idx of data region (byte 65536)
#define PAR_U64 32768   // u64 per parity: 16 groups * 16 members * 128
#define GRP_U64 2048    // u64 per group

#define ALD(P) __hip_atomic_load((P), __ATOMIC_RELAXED, __HIP_MEMORY_SCOPE_AGENT)
#define AST(P, V) __hip_atomic_store((P), (V), __ATOMIC_RELAXED, __HIP_MEMORY_SCOPE_AGENT)
#define VMWAIT()                                                               \
  do {                                                                         \
    asm volatile("s_waitcnt vmcnt(0)" ::: "memory");                           \
    __builtin_amdgcn_sched_barrier(0);                                         \
  } while (0)

__device__ __forceinline__ ushort_t bf16_rne(float f) {
  uint_t u = __float_as_uint(f);
  return (ushort_t)((u + 0x7fffu + ((u >> 16) & 1u)) >> 16);
}
__device__ __forceinline__ float bf16f(ushort_t h) {
  return __uint_as_float(((uint_t)h) << 16);
}
__device__ __forceinline__ int gRow(int rs, int m) {
  int base = m * NJ;
  if (rs < 32) return base + rs;
  if (rs < 64) return 512 + base + (rs - 32);
  return 1024 + base + (rs - 64);
}

template <bool LO>
__device__ __forceinline__ void loadW(short8* dst, const float* __restrict__ W,
                                      int tile, int m, int lane) {
  int rs = tile * 16 + (lane & 15);
  const float* p = W + (size_t)gRow(rs, m) * 512 + ((lane >> 4) << 3);
#pragma unroll
  for (int c = 0; c < 16; ++c) {
    const float* pc = p + c * 32;
    short8 o;
#pragma unroll
    for (int i = 0; i < 8; ++i) {
      float v = pc[i];
      ushort_t hi = bf16_rne(v);
      o[i] = LO ? (short)bf16_rne(v - bf16f(hi)) : (short)hi;
    }
    dst[c] = o;
  }
}

__global__ __launch_bounds__(TPB, 1) void gru_kernel(
    const float* __restrict__ x, const float* __restrict__ Wih,
    const float* __restrict__ Whh, const float* __restrict__ bih,
    const float* __restrict__ bhh, float* __restrict__ out,
    uint_t* __restrict__ wsp, int NT) {
  __shared__ __align__(16) uint_t s_pb[4096];  // 16KB: 16 chunks x 1KB (hi)
  __shared__ __align__(16) uint_t s_xlo[4096]; // x lo-planes (gi phase only)
  __shared__ float s_gi[96 * 17];
  __shared__ float s_gh[96 * 17];
  __shared__ float s_hloc[NB * NJ]; // own h slice, f32 across steps
  __shared__ float s_bhh[NJ];
  __shared__ int s_stop;

  const int tid = threadIdx.x;
  const int lane = tid & 63;
  const int w = tid >> 6;
  const int bid = blockIdx.x;
  const int g = bid & 15;
  const int m = bid >> 4;
  const int me = (g << 4) + m;
  if (NT <= 0) return;

  uint_t* flagsu = wsp;
  u64_t* gq = (u64_t*)(wsp + GBUF_BASE);

  // ---- stage relu(x) as hi plane (s_pb) + lo plane (s_xlo) ----
  for (int i = tid; i < 1024; i += TPB) {
    int b = i >> 6, k0 = (i & 63) << 3;
    const float* px = x + (size_t)(g * NB + b) * 512 + k0;
    u32x4 vh, vl;
#pragma unroll
    for (int jj = 0; jj < 4; ++jj) {
      float f0 = px[2 * jj], f1 = px[2 * jj + 1];
      f0 = f0 > 0.f ? f0 : 0.f;
      f1 = f1 > 0.f ? f1 : 0.f;
      ushort_t h0 = bf16_rne(f0), h1 = bf16_rne(f1);
      vh[jj] = (uint_t)h0 | ((uint_t)h1 << 16);
      vl[jj] = (uint_t)bf16_rne(f0 - bf16f(h0)) |
               ((uint_t)bf16_rne(f1 - bf16f(h1)) << 16);
    }
    int c = k0 >> 5, kk = k0 & 31;
    int base = c * 1024 + ((((b << 6) + (kk << 1))) ^ ((b & 7) << 4));
    *(u32x4*)((char*)s_pb + base) = vh;
    *(u32x4*)((char*)s_xlo + base) = vl;
  }
  if (tid < NJ) s_bhh[tid] = bhh[1024 + m * NJ + tid];
  if (tid == 0) s_stop = 0;
  __syncthreads();

  short8 wA[16], wB[16];
  const f32x4 vzero = {0.f, 0.f, 0.f, 0.f};
  const int bcol = lane & 15;
  const int roff = ((bcol << 6) + ((lane >> 4) << 4)) ^ ((bcol & 7) << 4);
  const char* pb = (const char*)s_pb;
  const char* pxl = (const char*)s_xlo;

  // ---- gi = relu(x) @ W_ih^T (3-term hi/lo split) ----
  f32x4 acc0 = vzero, acc1 = vzero;
  if (w < 3) {
    loadW<false>(wA, Wih, 2 * w, m, lane);
    loadW<false>(wB, Wih, 2 * w + 1, m, lane);
    {
      f32x4 a0h = vzero, a0l = vzero, a1h = vzero, a1l = vzero;
#pragma unroll
      for (int c = 0; c < 16; ++c) {
        short8 bh = *(const short8*)(pb + c * 1024 + roff);
        short8 bl = *(const short8*)(pxl + c * 1024 + roff);
        a0h = __builtin_amdgcn_mfma_f32_16x16x32_bf16(wA[c], bh, a0h, 0, 0, 0);
        a1h = __builtin_amdgcn_mfma_f32_16x16x32_bf16(wB[c], bh, a1h, 0, 0, 0);
        a0l = __builtin_amdgcn_mfma_f32_16x16x32_bf16(wA[c], bl, a0l, 0, 0, 0);
        a1l = __builtin_amdgcn_mfma_f32_16x16x32_bf16(wB[c], bl, a1l, 0, 0, 0);
      }
      acc0 = a0h + a0l;
      acc1 = a1h + a1l;
    }
    loadW<true>(wA, Wih, 2 * w, m, lane);
    loadW<true>(wB, Wih, 2 * w + 1, m, lane);
#pragma unroll
    for (int c = 0; c < 16; ++c) {
      short8 bh = *(const short8*)(pb + c * 1024 + roff);
      acc0 = __builtin_amdgcn_mfma_f32_16x16x32_bf16(wA[c], bh, acc0, 0, 0, 0);
      acc1 = __builtin_amdgcn_mfma_f32_16x16x32_bf16(wB[c], bh, acc1, 0, 0, 0);
    }
  }
  __syncthreads();
  if (w < 3) {
    int drow = (lane >> 4) << 2;
#pragma unroll
    for (int q = 0; q < 4; ++q) {
      int rs0 = 2 * w * 16 + drow + q, rs1 = rs0 + 16;
      int g0 = gRow(rs0, m), g1 = gRow(rs1, m);
      s_gi[rs0 * 17 + bcol] = acc0[q] + bih[g0] + (rs0 < 64 ? bhh[g0] : 0.f);
      s_gi[rs1 * 17 + bcol] = acc1[q] + bih[g1] + (rs1 < 64 ? bhh[g1] : 0.f);
    }
    loadW<false>(wA, Whh, 2 * w, m, lane); // W_hh resident from here
    loadW<false>(wB, Whh, 2 * w + 1, m, lane);
  }
  for (int i = tid; i < 4096; i += TPB) s_pb[i] = 0u; // h0 = 0
  for (int i = tid; i < NB * NJ; i += TPB) s_hloc[i] = 0.f;
  __syncthreads();

  const size_t outRow = (size_t)NT * 512;
  float* outBase = out + (size_t)(g * NB) * outRow + m * NJ;

  for (int t = 0; t < NT; ++t) {
    const int xpar = (t + 1) & 1;
    // ---- phase 1: gh = W_hh @ h_hi from LDS chunks (waves 0-2) ----
    if (w < 3) {
      f32x4 aE0 = vzero, aO0 = vzero, aE1 = vzero, aO1 = vzero;
#pragma unroll
      for (int p = 0; p < 16; p += 2) {
        short8 b0 = *(const short8*)(pb + p * 1024 + roff);
        short8 b1 = *(const short8*)(pb + (p + 1) * 1024 + roff);
        aE0 = __builtin_amdgcn_mfma_f32_16x16x32_bf16(wA[p], b0, aE0, 0, 0, 0);
        aE1 = __builtin_amdgcn_mfma_f32_16x16x32_bf16(wB[p], b0, aE1, 0, 0, 0);
        aO0 = __builtin_amdgcn_mfma_f32_16x16x32_bf16(wA[p + 1], b1, aO0, 0, 0, 0);
        aO1 = __builtin_amdgcn_mfma_f32_16x16x32_bf16(wB[p + 1], b1, aO1, 0, 0, 0);
      }
      f32x4 r0 = aE0 + aO0, r1 = aE1 + aO1;
      int drow = (lane >> 4) << 2;
#pragma unroll
      for (int q = 0; q < 4; ++q) {
        s_gh[(2 * w * 16 + drow + q) * 17 + bcol] = r0[q];
        s_gh[((2 * w + 1) * 16 + drow + q) * 17 + bcol] = r1[q];
      }
    }
    __syncthreads(); // barrier #1: s_gh ready; s_pb free for reload

    // ---- gates (waves 4-5): h(t+1); export -> drain -> own flag; out ----
    const int et = tid - 256;
    if (et >= 0) {
      int b = et >> 3, j0 = (et & 7) << 2;
      float hn[4];
#pragma unroll
      for (int e = 0; e < 4; ++e) {
        int j = j0 + e;
        float pr = s_gi[j * 17 + b] + s_gh[j * 17 + b];
        float pz = s_gi[(32 + j) * 17 + b] + s_gh[(32 + j) * 17 + b];
        float r = 1.f / (1.f + __expf(-pr));
        float z = 1.f / (1.f + __expf(-pz));
        float pn =
            s_gi[(64 + j) * 17 + b] + r * (s_gh[(64 + j) * 17 + b] + s_bhh[j]);
        float n = 1.f - 2.f / (1.f + __expf(2.f * pn));
        hn[e] = n + z * (s_hloc[b * 32 + j] - n);
        s_hloc[b * 32 + j] = hn[e];
      }
      if (t + 1 < NT) {
        uint_t d0 = (uint_t)bf16_rne(hn[0]) | ((uint_t)bf16_rne(hn[1]) << 16);
        uint_t d1 = (uint_t)bf16_rne(hn[2]) | ((uint_t)bf16_rne(hn[3]) << 16);
        u64_t pq = (u64_t)d0 | ((u64_t)d1 << 32);
        u64_t* dst = gq + (size_t)xpar * PAR_U64 + g * GRP_U64 + (m << 7) +
                     (b << 3) + (et & 7);
        AST(dst, pq);
        VMWAIT(); // own export acked at coherence point (producer-only drain)
        if (lane == 0)
          AST(&flagsu[(me << 5) + ((w - 4) << 3)], (uint_t)(t + 1));
      }
      f32x4 ov = {hn[0], hn[1], hn[2], hn[3]};
      __builtin_nontemporal_store(
          ov, (f32x4*)(outBase + (size_t)b * outRow + (size_t)t * 512 + j0));
    }

    // ---- pollers (waves 0-3): poll 4 peers x 2 flags, then reload ----
    if (w < 4 && t + 1 < NT) {
      const uint_t tgt = (uint_t)(t + 1);
      int ok = 1;
      {
        uint_t sp = 0;
        uint_t* fp = flagsu +
                     ((((g << 4) + (w << 2) + (lane >> 1)) << 5) +
                      ((lane & 1) << 3));
        for (;;) {
          uint_t v = tgt;
          if (lane < 8) v = ALD(fp);
          if (__all((int)(v >= tgt))) break;
          ++sp;
          uint_t ab = 0;
          if ((sp & 127u) == 0u) {
            ab = ALD(&flagsu[ABORT_IDX]);
            if (sp > SPIN_MAX) {
              AST(&flagsu[ABORT_IDX], 1u);
              ab = 1;
            }
          }
          if (__any((int)(ab != 0))) {
            if (lane == 0) s_stop = 1;
            ok = 0;
            break;
          }
          __builtin_amdgcn_s_sleep(1);
        }
      }
      if (ok) { // reload this wave's 4 peers: 8 u64/lane, batched
        const u64_t* srcq =
            gq + (size_t)xpar * PAR_U64 + g * GRP_U64 + (w << 9);
#define LDI(k) ALD(srcq + lane + ((k) << 6))
        u64_t q0 = LDI(0), q1 = LDI(1), q2 = LDI(2), q3 = LDI(3);
        u64_t q4 = LDI(4), q5 = LDI(5), q6 = LDI(6), q7 = LDI(7);
#undef LDI
#define STI(k, qq)                                                             \
  {                                                                            \
    uint_t qb = (uint_t)(((w << 9) + lane + ((k) << 6)) << 3);                 \
    *(u64_t*)((char*)s_pb + (qb ^ (((qb >> 6) & 7u) << 4))) = (qq);            \
  }
        STI(0, q0) STI(1, q1) STI(2, q2) STI(3, q3)
        STI(4, q4) STI(5, q5) STI(6, q6) STI(7, q7)
#undef STI
      }
    }
    __syncthreads(); // barrier #2: reload visible; out-stores drained
    if (s_stop) break;
  }
}

extern "C" void kernel_launch(void* const* d_in, const int* in_sizes, int n_in,
                              void* d_out, int out_size, void* d_ws,
                              size_t ws_size, hipStream_t stream) {
  const float* x = (const float*)d_in[0];
  const float* Wih = (const float*)d_in[1];
  const float* Whh = (const float*)d_in[2];
  const float* bih = (const float*)d_in[3];
  const float* bhh = (const float*)d_in[4];
  float* out = (float*)d_out;
  int NT = out_size / (256 * 512);
  // ws: [0,32KB) flags (128B/member, 2 slots) + abort @32KB;
  // data @64KB: 2 parities x 256KB (hi-plane h exchange).
  uint_t* wsp = (uint_t*)d_ws;
  (void)hipMemsetAsync(d_ws, 0, 65536, stream);
  hipLaunchKernelGGL(gru_kernel, dim3(NG * NM), dim3(TPB), 0, stream, x, Wih,
                     Whh, bih, bhh, out, wsp, NT);
}